// Round 26
// baseline (185.812 us; speedup 1.0000x reference)
//
#include <hip/hip_runtime.h>

typedef float    f4 __attribute__((ext_vector_type(4)));
typedef float    f2 __attribute__((ext_vector_type(2)));
typedef _Float16 h8 __attribute__((ext_vector_type(8)));

#define B_ 32
#define D_ 128
#define T_ 1024
#define K_ 4096
#define NROWS (B_ * T_)   // 32768
#define LPX 132
#define INF_ 3.4e38f

#define MFMA16 __builtin_amdgcn_mfma_f32_16x16x32_f16

// numpy computes t = a*a elementwise, THEN pairwise-sums (no fma fusion).
__device__ __forceinline__ float opaquef(float x) { asm volatile("" : "+v"(x)); return x; }

// numpy pairwise_sum base case for n=128: 8 accumulators,
// ((r0+r1)+(r2+r3))+((r4+r5)+(r6+r7)). Bit-exact replica (r12-proven).
__device__ float np_sumsq128(const float* a) {
  float r[8];
#pragma unroll
  for (int j = 0; j < 8; ++j) r[j] = opaquef(a[j] * a[j]);
#pragma unroll
  for (int i = 8; i < 128; i += 8) {
#pragma unroll
    for (int j = 0; j < 8; ++j) r[j] = r[j] + opaquef(a[i + j] * a[i + j]);
  }
  return ((r[0] + r[1]) + (r[2] + r[3])) + ((r[4] + r[5]) + (r[6] + r[7]));
}

// Fused prep (r24-green): every thread writes one fp16 Wbf element (scaled by
// 4096, exact power-of-2; Ws ~ N(0,1) avoids fp16 subnormals); first 4096
// threads also compute wsq (np-order chain) + maxwsq; threads e<NROWS init
// cnt/flags/eslot; thread 0 inits nflag.
// Wbf elem e = ((ct*4+kk)*64+lane)*8+j holds fp16(4096*W[ct*16+(lane&15)][kk*32+((lane>>4)&3)*8+j])
__global__ void prep_kernel(const float* __restrict__ W, _Float16* __restrict__ Wbf,
                            float* __restrict__ wsq, unsigned* __restrict__ maxwsq,
                            int* __restrict__ cnt, int* __restrict__ flags,
                            unsigned long long* __restrict__ eslot,
                            int* __restrict__ nflag) {
  int e = blockIdx.x * 256 + threadIdx.x;   // 524288 total
  int j = e & 7, lane = (e >> 3) & 63, kk = (e >> 9) & 3, ct = e >> 11;
  int code = (ct << 4) + (lane & 15);
  int k = (kk << 5) + (((lane >> 4) & 3) << 3) + j;
  Wbf[e] = (_Float16)(W[(size_t)code * D_ + k] * 4096.0f);
  if (e < NROWS) {
    cnt[e] = 0;
    flags[e] = 0;
    eslot[e] = 0xFFFFFFFFFFFFFFFFull;
  }
  if (e == 0) *nflag = 0;
  if (e < K_) {
    float s = np_sumsq128(W + (size_t)e * D_);
    wsq[e] = s;
    atomicMax(maxwsq, __float_as_uint(s));  // positive floats: uint order == float order
  }
}

// B-fragment load: linear byte pointer + imm offsets (r14-proven)
#define LDB(R0, R1, R2, R3, WQ)               \
  R0 = *(const h8*)(pwb);                     \
  R1 = *(const h8*)(pwb + 1024);              \
  R2 = *(const h8*)(pwb + 2048);              \
  R3 = *(const h8*)(pwb + 3072);              \
  WQ = *pwq;                                  \
  pwb += 4096; pwq += 16;

// top-2+m3 tracker (r15/r18-r25-validated): m1<=m2<=m3; i1,i2 track m1,m2
#define TOP3_UPD(T, J, U, KK)                                                  \
  do {                                                                         \
    bool c1 = (U) < m1[T][J], c2 = (U) < m2[T][J];                             \
    m3[T][J] = __builtin_amdgcn_fmed3f((U), m2[T][J], m3[T][J]);               \
    m2[T][J] = __builtin_amdgcn_fmed3f((U), m1[T][J], m2[T][J]);               \
    m1[T][J] = fminf((U), m1[T][J]);                                           \
    i2[T][J] = c1 ? i1[T][J] : (c2 ? (KK) : i2[T][J]);                         \
    i1[T][J] = c1 ? (KK) : i1[T][J];                                           \
  } while (0)

// Single-sweep fp16 consume: 8 MFMAs (2 chains x 2 row-tiles; chain-split
// covered by WIN's accum margin). acc = 4096*mm => u = wq - acc/2048
// (exact power-of-2 unscale). Then per-slot top-3 tracking.
#define CONSUME_MIN(B0, B1, B2, B3, WQ, CT)                                    \
  do {                                                                         \
    f4 z = {0.f, 0.f, 0.f, 0.f};                                               \
    f4 A0 = MFMA16(afr0[0], B0, z, 0, 0, 0);                                   \
    A0 = MFMA16(afr0[1], B1, A0, 0, 0, 0);                                     \
    f4 A1 = MFMA16(afr0[2], B2, z, 0, 0, 0);                                   \
    A1 = MFMA16(afr0[3], B3, A1, 0, 0, 0);                                     \
    f4 C0 = MFMA16(afr1[0], B0, z, 0, 0, 0);                                   \
    C0 = MFMA16(afr1[1], B1, C0, 0, 0, 0);                                     \
    f4 C1 = MFMA16(afr1[2], B2, z, 0, 0, 0);                                   \
    C1 = MFMA16(afr1[3], B3, C1, 0, 0, 0);                                     \
    const int kk_ = ((CT) << 4) + cidx;                                        \
    _Pragma("unroll")                                                          \
    for (int j = 0; j < 4; ++j) {                                              \
      float u0 = __fmaf_rn(-4.8828125e-4f, A0[j] + A1[j], WQ);                 \
      TOP3_UPD(0, j, u0, kk_);                                                 \
      float u1 = __fmaf_rn(-4.8828125e-4f, C0[j] + C1[j], WQ);                 \
      TOP3_UPD(1, j, u1, kk_);                                                 \
    }                                                                          \
  } while (0)

// Single-sweep fp16 MFMA filter, r26: 512 threads / 8 waves per block, each
// wave sweeps a 32-ct half-quarter (block still covers all 4096 codes for its
// 32 rows; L2 traffic unchanged). More resident waves (~6/SIMD at 76 VGPR)
// cover the MFMA/L2 latency that 2-3 blocks/CU could not. NOTE: plain
// __launch_bounds__(512) — the (512,4) form cuts the VGPR budget to 64 and
// spills this body (r8 lesson). Window = rigorous fp16 bound (r21-r25).
__global__ __launch_bounds__(512) void filter_kernel(
    const float* __restrict__ x, const _Float16* __restrict__ Wbf,
    const float* __restrict__ wsq, const unsigned* __restrict__ maxwsq,
    float* __restrict__ xsq_g, int* __restrict__ cnt, int* __restrict__ cand,
    int* __restrict__ flags, int* __restrict__ nflag, int* __restrict__ flist) {
  __shared__ float xs[32][LPX];
  __shared__ float xsqs[32];
  __shared__ float umin_sh[32][8];
  const int tid = threadIdx.x;
  const int blkrow = blockIdx.x * 32;
  const int b = blockIdx.x >> 5, t0 = (blockIdx.x & 31) << 5;

  {  // stage x rows (coalesced along t): 512 threads, 8 elems each
    int tt = tid & 31, d0 = (tid >> 5) * 8;
    for (int dd = 0; dd < 8; ++dd) {
      int d = d0 + dd;
      xs[tt][d] = x[((size_t)b * D_ + d) * T_ + t0 + tt];
    }
  }
  __syncthreads();
  if (tid < 32) {
    float s = np_sumsq128(&xs[tid][0]);
    xsqs[tid] = s;
    xsq_g[blkrow + tid] = s;
  }
  __syncthreads();

  const int w = tid >> 6, lane = tid & 63;   // w in 0..7
  const int cidx = lane & 15;         // code within ct tile
  const int q = lane >> 4;            // k-slice / C-row group

  // A fragments (fp16 x, unscaled) for both row-tiles:
  // row t*16+(lane&15), k = kk*32+q*8+j
  h8 afr0[4], afr1[4];
#pragma unroll
  for (int kk = 0; kk < 4; ++kk)
#pragma unroll
    for (int j = 0; j < 8; ++j) {
      int k = (kk << 5) + (q << 3) + j;
      afr0[kk][j] = (_Float16)xs[cidx][k];
      afr1[kk][j] = (_Float16)xs[16 + cidx][k];
    }

  const float mw = sqrtf(__uint_as_float(*maxwsq)) * 1.0001f;

  float m1[2][4], m2[2][4], m3[2][4];
  int   i1[2][4], i2[2][4];
#pragma unroll
  for (int t = 0; t < 2; ++t)
#pragma unroll
    for (int j = 0; j < 4; ++j) {
      m1[t][j] = INF_; m2[t][j] = INF_; m3[t][j] = INF_;
      i1[t][j] = 0x7fffffff; i2[t][j] = 0x7fffffff;
    }
  const int ct0 = w << 5;             // this wave's 32-ct slice

  {
    const char*  pwb = (const char*)Wbf + (size_t)ct0 * 4096 + (size_t)lane * 16;
    const float* pwq = wsq + (ct0 << 4) + cidx;
    h8 p0, p1, p2, p3, n0, n1, n2, n3;
    float wqc, wqn;
    LDB(p0, p1, p2, p3, wqc)          // ct0
    for (int s = 0; s < 16; ++s) {
      const int c = ct0 + s * 2;
      LDB(n0, n1, n2, n3, wqn)        // ct0+2s+1
      CONSUME_MIN(p0, p1, p2, p3, wqc, c);
      LDB(p0, p1, p2, p3, wqc)        // ct0+2s+2 (last iter overreads mapped slack)
      CONSUME_MIN(n0, n1, n2, n3, wqn, c + 1);
    }
  }

  // min over the 16 code-lanes (butterfly) -> per-row slice-min
  float lim[2][4];
#pragma unroll
  for (int t = 0; t < 2; ++t)
#pragma unroll
    for (int j = 0; j < 4; ++j) {
      float m = m1[t][j];
#pragma unroll
      for (int mask = 1; mask < 16; mask <<= 1)
        m = fminf(m, __shfl_xor(m, mask));
      if (cidx == 0) umin_sh[t * 16 + (q << 2) + j][w] = m;
    }
  __syncthreads();
  // merge 8 slices + window. Rigorous: 2*err_u = 0.0039*xn*mw (we use
  // 2.2*0.002 = 13% margin, covers MFMA accum too); +4e-5 covers the
  // +xsq rounding bin (<=3.05e-5 for xsq in [128,256)) + 1e-5 misc.
#pragma unroll
  for (int t = 0; t < 2; ++t)
#pragma unroll
    for (int j = 0; j < 4; ++j) {
      int rl = t * 16 + (q << 2) + j;
      float mg = umin_sh[rl][0];
#pragma unroll
      for (int ww = 1; ww < 8; ++ww) mg = fminf(mg, umin_sh[rl][ww]);
      float xn = sqrtf(xsqs[rl]) * 1.0001f;
      lim[t][j] = mg + 2.2f * (0.002f * xn * mw) + 4e-5f;
    }

  // insertion: top-2 if within window; m3 within window (or overflow) => flag
#pragma unroll
  for (int t = 0; t < 2; ++t)
#pragma unroll
    for (int j = 0; j < 4; ++j) {
      int row = blkrow + t * 16 + (q << 2) + j;
      bool ovf = false;
      if (m1[t][j] <= lim[t][j]) {
        int pos = atomicAdd(&cnt[row], 1);
        if (pos < 16) cand[(row << 4) + pos] = i1[t][j]; else ovf = true;
      }
      if (m2[t][j] <= lim[t][j]) {
        int pos = atomicAdd(&cnt[row], 1);
        if (pos < 16) cand[(row << 4) + pos] = i2[t][j]; else ovf = true;
      }
      if (ovf || m3[t][j] <= lim[t][j]) {
        int old = atomicOr(&flags[row], 1);
        if (old == 0) { int p = atomicAdd(nflag, 1); flist[p & (NROWS - 1)] = row; }
      }
    }
}

// Exact rescore: lane c replays the bit-exact np fp32 pipeline for candidate c;
// lexicographic (v, k) min == np.argmin first-occurrence. (r16/r18-r25-proven)
__global__ __launch_bounds__(256) void rescore_kernel(
    const float* __restrict__ x, const float* __restrict__ W,
    const float* __restrict__ wsq, const float* __restrict__ xsq,
    const int* __restrict__ cnt, const int* __restrict__ cand,
    const int* __restrict__ flags,
    int* __restrict__ qout, float* __restrict__ out2) {
  const int wid = threadIdx.x >> 6, lane = threadIdx.x & 63;
  const int r = blockIdx.x * 4 + wid;
  if (flags[r]) return;   // exact path owns this row
  int c = cnt[r]; if (c > 16) c = 16;
  int best;
  if (c == 1) {
    best = cand[r << 4] & (K_ - 1);
  } else {
    const float* xr = x + ((size_t)(r >> 10) * D_) * T_ + (r & 1023);
    float v = INF_; int k = 0x7fffffff;
    if (lane < c) {
      k = cand[(r << 4) + lane] & (K_ - 1);
      const float* wr = W + (size_t)k * D_;
      float mm = 0.f;
#pragma unroll 16
      for (int d = 0; d < D_; ++d)
        mm = __fmaf_rn(xr[(size_t)d * T_], wr[d], mm);   // ascending-d sgemm chain
      v = __fadd_rn(__fmaf_rn(-2.f, mm, wsq[k]), xsq[r]);  // RN(wq-2mm) then +xsq
    }
#pragma unroll
    for (int mask = 1; mask < 16; mask <<= 1) {
      float vo = __shfl_xor(v, mask); int ko = __shfl_xor(k, mask);
      if (vo < v || (vo == v && ko < k)) { v = vo; k = ko; }
    }
    best = k & (K_ - 1);
  }
  if (lane == 0) { qout[r] = best; out2[r] = (float)best; }
}

// Exact full-scan for flagged rows (expected ~0-10). Work item = (row,
// k-chunk of 512): 8-way parallel per row; partial lex-min merged via u64
// atomicMin (deterministic: same values every replay). LDS-staged coalesced W.
__global__ __launch_bounds__(256) void exact_kernel(
    const float* __restrict__ x, const float* __restrict__ W,
    const float* __restrict__ wsq, const float* __restrict__ xsq,
    const int* __restrict__ nflag, const int* __restrict__ flist,
    unsigned long long* __restrict__ eslot) {
  __shared__ float xrow[128];
  __shared__ float wl[64][130];   // pad 130
  int n = *nflag; if (n > NROWS) n = NROWS;
  for (int item = blockIdx.x; item < n * 8; item += 256) {
    int r = flist[item >> 3] & (NROWS - 1);
    int chunk = item & 7;
    const float* xr = x + ((size_t)(r >> 10) * D_) * T_ + (r & 1023);
    __syncthreads();   // protect xrow/wl from previous item
    if (threadIdx.x < 128) xrow[threadIdx.x] = xr[(size_t)threadIdx.x * T_];
    float v = INF_; int kb = 0x7fffffff;
    for (int s = chunk * 8; s < chunk * 8 + 8; ++s) {
      __syncthreads();
      const f2* src = (const f2*)(W + (size_t)s * 64 * D_);
      for (int e = threadIdx.x; e < 4096; e += 256)
        *(f2*)&wl[e >> 6][(e & 63) * 2] = src[e];
      __syncthreads();
      if (threadIdx.x < 64) {
        int k = s * 64 + threadIdx.x;
        float mm = 0.f;
#pragma unroll 16
        for (int d = 0; d < D_; ++d)
          mm = __fmaf_rn(xrow[d], wl[threadIdx.x][d], mm);  // ascending-d chain
        float vv = __fadd_rn(__fmaf_rn(-2.f, mm, wsq[k]), xsq[r]);
        if (vv < v) { v = vv; kb = k; }   // strict < ; k ascending per lane
      }
    }
    if (threadIdx.x < 64) {
#pragma unroll
      for (int mask = 1; mask < 64; mask <<= 1) {
        float vo = __shfl_xor(v, mask); int ko = __shfl_xor(kb, mask);
        if (vo < v || (vo == v && ko < kb)) { v = vo; kb = ko; }
      }
      if (threadIdx.x == 0) {
        // v > 0 (distance ~128) => float bits are order-preserving
        unsigned long long pk =
            ((unsigned long long)__float_as_uint(v) << 32) | (unsigned)kb;
        atomicMin(&eslot[r], pk);
      }
    }
    __syncthreads();
  }
}

// Write flagged rows' winners from the u64 slots.
__global__ void finalize_kernel(const int* __restrict__ flags,
                                const unsigned long long* __restrict__ eslot,
                                int* __restrict__ qout, float* __restrict__ out2) {
  int r = blockIdx.x * 256 + threadIdx.x;
  if (flags[r]) {
    int best = (int)(unsigned)(eslot[r] & 0xFFFFFFFFull) & (K_ - 1);
    qout[r] = best; out2[r] = (float)best;
  }
}

// Fused scatter (r24-green): blocks [0, NROWS/2) do out0[r,d]=W[q[r],d]
// (coalesced along d); remaining B*D blocks do out1[b,d,t]=W[q[b,t],d]
// (coalesced along t).
__global__ void scatter_kernel(const float* __restrict__ W,
                               const int* __restrict__ q,
                               float* __restrict__ out0, float* __restrict__ out1) {
  if (blockIdx.x < NROWS / 2) {
    int r = blockIdx.x * 2 + (threadIdx.x >> 7);
    int d = threadIdx.x & 127;
    int k = q[r] & (K_ - 1);
    out0[(size_t)r * D_ + d] = W[(size_t)k * D_ + d];
  } else {
    int bb = blockIdx.x - NROWS / 2;
    int b = bb >> 7, d = bb & 127;
    for (int t = threadIdx.x; t < T_; t += 256) {
      int k = q[b * T_ + t] & (K_ - 1);
      out1[((size_t)b * D_ + d) * T_ + t] = W[(size_t)k * D_ + d];
    }
  }
}

extern "C" void kernel_launch(void* const* d_in, const int* in_sizes, int n_in,
                              void* d_out, int out_size, void* d_ws, size_t ws_size,
                              hipStream_t stream) {
  const float* x = (const float*)d_in[0];
  const float* W = (const float*)d_in[1];
  float* out  = (float*)d_out;
  float* out0 = out;                           // [B,T,D]  4194304
  float* out1 = out + (size_t)NROWS * D_;      // [B,D,T]  4194304
  float* out2 = out + 2 * (size_t)NROWS * D_;  // [B,T]    32768 (as float)

  // small scratch in ws (532 KB, within the proven envelope)
  float*    wsq   = (float*)d_ws;                               // 16 KB
  float*    xsq   = (float*)((char*)d_ws + (16 << 10));         // 128 KB
  int*      q     = (int*)((char*)d_ws + (144 << 10));          // 128 KB
  int*      cnt   = (int*)((char*)d_ws + (272 << 10));          // 128 KB
  unsigned* maxw  = (unsigned*)((char*)d_ws + (400 << 10));     // 4 B (4K pad)
  int*      flags = (int*)((char*)d_ws + (404 << 10));          // 128 KB

  // big scratch in out0 (read before scatter overwrites it; stream-ordered)
  int*      cand  = (int*)out0;                                    // 2 MB
  _Float16* Wbf   = (_Float16*)((char*)(void*)out0 + (2 << 20));   // 1 MB
  int*      flist = (int*)((char*)(void*)out0 + (3 << 20));        // 128 KB (also LDB overread slack)
  int*      nflag = (int*)((char*)(void*)out0 + (3 << 20) + (128 << 10));  // 64 B
  unsigned long long* eslot =
      (unsigned long long*)((char*)(void*)out0 + (3 << 20) + (256 << 10));  // 256 KB

  // maxw must be zero BEFORE prep's atomicMax (cross-block race if done inside)
  hipMemsetAsync(maxw, 0, 64, stream);
  prep_kernel<<<K_ * D_ / 256, 256, 0, stream>>>(W, Wbf, wsq, maxw,
                                                 cnt, flags, eslot, nflag);
  filter_kernel<<<NROWS / 32, 512, 0, stream>>>(x, Wbf, wsq, maxw, xsq,
                                                cnt, cand, flags, nflag, flist);
  rescore_kernel<<<NROWS / 4, 256, 0, stream>>>(x, W, wsq, xsq, cnt, cand, flags, q, out2);
  exact_kernel<<<256, 256, 0, stream>>>(x, W, wsq, xsq, nflag, flist, eslot);
  finalize_kernel<<<NROWS / 256, 256, 0, stream>>>(flags, eslot, q, out2);
  scatter_kernel<<<NROWS / 2 + B_ * D_, 256, 0, stream>>>(W, q, out0, out1);
}

// Round 27
// 165.662 us; speedup vs baseline: 1.1216x; 1.1216x over previous
//
#include <hip/hip_runtime.h>

typedef float    f4 __attribute__((ext_vector_type(4)));
typedef float    f2 __attribute__((ext_vector_type(2)));
typedef _Float16 h8 __attribute__((ext_vector_type(8)));

#define B_ 32
#define D_ 128
#define T_ 1024
#define K_ 4096
#define NROWS (B_ * T_)   // 32768
#define LPX 132
#define INF_ 3.4e38f

#define MFMA16 __builtin_amdgcn_mfma_f32_16x16x32_f16

// numpy computes t = a*a elementwise, THEN pairwise-sums (no fma fusion).
__device__ __forceinline__ float opaquef(float x) { asm volatile("" : "+v"(x)); return x; }

// numpy pairwise_sum base case for n=128: 8 accumulators,
// ((r0+r1)+(r2+r3))+((r4+r5)+(r6+r7)). Bit-exact replica (r12-proven).
__device__ float np_sumsq128(const float* a) {
  float r[8];
#pragma unroll
  for (int j = 0; j < 8; ++j) r[j] = opaquef(a[j] * a[j]);
#pragma unroll
  for (int i = 8; i < 128; i += 8) {
#pragma unroll
    for (int j = 0; j < 8; ++j) r[j] = r[j] + opaquef(a[i + j] * a[i + j]);
  }
  return ((r[0] + r[1]) + (r[2] + r[3])) + ((r[4] + r[5]) + (r[6] + r[7]));
}

// Fused prep (r24/r25-green): every thread writes one fp16 Wbf element (scaled
// by 4096, exact power-of-2; Ws ~ N(0,1) avoids fp16 subnormals); first 4096
// threads also compute wsq (np-order chain) + maxwsq; threads e<NROWS init
// cnt/flags/eslot; thread 0 inits nflag.
// Wbf elem e = ((ct*4+kk)*64+lane)*8+j holds fp16(4096*W[ct*16+(lane&15)][kk*32+((lane>>4)&3)*8+j])
__global__ void prep_kernel(const float* __restrict__ W, _Float16* __restrict__ Wbf,
                            float* __restrict__ wsq, unsigned* __restrict__ maxwsq,
                            int* __restrict__ cnt, int* __restrict__ flags,
                            unsigned long long* __restrict__ eslot,
                            int* __restrict__ nflag) {
  int e = blockIdx.x * 256 + threadIdx.x;   // 524288 total
  int j = e & 7, lane = (e >> 3) & 63, kk = (e >> 9) & 3, ct = e >> 11;
  int code = (ct << 4) + (lane & 15);
  int k = (kk << 5) + (((lane >> 4) & 3) << 3) + j;
  Wbf[e] = (_Float16)(W[(size_t)code * D_ + k] * 4096.0f);
  if (e < NROWS) {
    cnt[e] = 0;
    flags[e] = 0;
    eslot[e] = 0xFFFFFFFFFFFFFFFFull;
  }
  if (e == 0) *nflag = 0;
  if (e < K_) {
    float s = np_sumsq128(W + (size_t)e * D_);
    wsq[e] = s;
    atomicMax(maxwsq, __float_as_uint(s));  // positive floats: uint order == float order
  }
}

// B-fragment load: linear byte pointer + imm offsets (r14-proven)
#define LDB(R0, R1, R2, R3, WQ)               \
  R0 = *(const h8*)(pwb);                     \
  R1 = *(const h8*)(pwb + 1024);              \
  R2 = *(const h8*)(pwb + 2048);              \
  R3 = *(const h8*)(pwb + 3072);              \
  WQ = *pwq;                                  \
  pwb += 4096; pwq += 16;

// top-2+m3 tracker (r15/r18-r25-validated): m1<=m2<=m3; i1,i2 track m1,m2
#define TOP3_UPD(T, J, U, KK)                                                  \
  do {                                                                         \
    bool c1 = (U) < m1[T][J], c2 = (U) < m2[T][J];                             \
    m3[T][J] = __builtin_amdgcn_fmed3f((U), m2[T][J], m3[T][J]);               \
    m2[T][J] = __builtin_amdgcn_fmed3f((U), m1[T][J], m2[T][J]);               \
    m1[T][J] = fminf((U), m1[T][J]);                                           \
    i2[T][J] = c1 ? i1[T][J] : (c2 ? (KK) : i2[T][J]);                         \
    i1[T][J] = c1 ? (KK) : i1[T][J];                                           \
  } while (0)

// Single-sweep fp16 consume: 8 MFMAs (2 chains x 2 row-tiles; chain-split
// covered by WIN's accum margin). acc = 4096*mm => u = wq - acc/2048
// (exact power-of-2 unscale). Then per-slot top-3 tracking.
#define CONSUME_MIN(B0, B1, B2, B3, WQ, CT)                                    \
  do {                                                                         \
    f4 z = {0.f, 0.f, 0.f, 0.f};                                               \
    f4 A0 = MFMA16(afr0[0], B0, z, 0, 0, 0);                                   \
    A0 = MFMA16(afr0[1], B1, A0, 0, 0, 0);                                     \
    f4 A1 = MFMA16(afr0[2], B2, z, 0, 0, 0);                                   \
    A1 = MFMA16(afr0[3], B3, A1, 0, 0, 0);                                     \
    f4 C0 = MFMA16(afr1[0], B0, z, 0, 0, 0);                                   \
    C0 = MFMA16(afr1[1], B1, C0, 0, 0, 0);                                     \
    f4 C1 = MFMA16(afr1[2], B2, z, 0, 0, 0);                                   \
    C1 = MFMA16(afr1[3], B3, C1, 0, 0, 0);                                     \
    const int kk_ = ((CT) << 4) + cidx;                                        \
    _Pragma("unroll")                                                          \
    for (int j = 0; j < 4; ++j) {                                              \
      float u0 = __fmaf_rn(-4.8828125e-4f, A0[j] + A1[j], WQ);                 \
      TOP3_UPD(0, j, u0, kk_);                                                 \
      float u1 = __fmaf_rn(-4.8828125e-4f, C0[j] + C1[j], WQ);                 \
      TOP3_UPD(1, j, u1, kk_);                                                 \
    }                                                                          \
  } while (0)

// Single-sweep fp16 MFMA filter (r21/r23/r25-proven configuration, ~105 us;
// measured local optimum: fences (r22), deeper prefetch (r13), 512-thr (r26)
// all regressed). Window = rigorous fp16 bound: err_u <= 2*(2*2^-11)*xn*mw
// (products exact in fp32, Cauchy-Schwarz, accum <= 7.6e-6*xn*mw);
// coverage = 2*err_u + xsq-bin.
__global__ __launch_bounds__(256) void filter_kernel(
    const float* __restrict__ x, const _Float16* __restrict__ Wbf,
    const float* __restrict__ wsq, const unsigned* __restrict__ maxwsq,
    float* __restrict__ xsq_g, int* __restrict__ cnt, int* __restrict__ cand,
    int* __restrict__ flags, int* __restrict__ nflag, int* __restrict__ flist) {
  __shared__ float xs[32][LPX];
  __shared__ float xsqs[32];
  __shared__ float umin_sh[32][4];
  const int tid = threadIdx.x;
  const int blkrow = blockIdx.x * 32;
  const int b = blockIdx.x >> 5, t0 = (blockIdx.x & 31) << 5;

  {  // stage x rows (coalesced along t)
    int tt = tid & 31, d0 = (tid >> 5) * 16;
    for (int dd = 0; dd < 16; ++dd) {
      int d = d0 + dd;
      xs[tt][d] = x[((size_t)b * D_ + d) * T_ + t0 + tt];
    }
  }
  __syncthreads();
  if (tid < 32) {
    float s = np_sumsq128(&xs[tid][0]);
    xsqs[tid] = s;
    xsq_g[blkrow + tid] = s;
  }
  __syncthreads();

  const int w = tid >> 6, lane = tid & 63;
  const int cidx = lane & 15;         // code within ct tile
  const int q = lane >> 4;            // k-slice / C-row group

  // A fragments (fp16 x, unscaled) for both row-tiles:
  // row t*16+(lane&15), k = kk*32+q*8+j
  h8 afr0[4], afr1[4];
#pragma unroll
  for (int kk = 0; kk < 4; ++kk)
#pragma unroll
    for (int j = 0; j < 8; ++j) {
      int k = (kk << 5) + (q << 3) + j;
      afr0[kk][j] = (_Float16)xs[cidx][k];
      afr1[kk][j] = (_Float16)xs[16 + cidx][k];
    }

  const float mw = sqrtf(__uint_as_float(*maxwsq)) * 1.0001f;

  float m1[2][4], m2[2][4], m3[2][4];
  int   i1[2][4], i2[2][4];
#pragma unroll
  for (int t = 0; t < 2; ++t)
#pragma unroll
    for (int j = 0; j < 4; ++j) {
      m1[t][j] = INF_; m2[t][j] = INF_; m3[t][j] = INF_;
      i1[t][j] = 0x7fffffff; i2[t][j] = 0x7fffffff;
    }
  const int ct0 = w << 6;             // this wave's 64-ct quarter

  {
    const char*  pwb = (const char*)Wbf + (size_t)ct0 * 4096 + (size_t)lane * 16;
    const float* pwq = wsq + (ct0 << 4) + cidx;
    h8 p0, p1, p2, p3, n0, n1, n2, n3;
    float wqc, wqn;
    LDB(p0, p1, p2, p3, wqc)          // ct0
    for (int s = 0; s < 32; ++s) {
      const int c = ct0 + s * 2;
      LDB(n0, n1, n2, n3, wqn)        // ct0+2s+1
      CONSUME_MIN(p0, p1, p2, p3, wqc, c);
      LDB(p0, p1, p2, p3, wqc)        // ct0+2s+2 (last iter overreads mapped slack)
      CONSUME_MIN(n0, n1, n2, n3, wqn, c + 1);
    }
  }

  // min over the 16 code-lanes (butterfly) -> per-row quarter-min
  float lim[2][4];
#pragma unroll
  for (int t = 0; t < 2; ++t)
#pragma unroll
    for (int j = 0; j < 4; ++j) {
      float m = m1[t][j];
#pragma unroll
      for (int mask = 1; mask < 16; mask <<= 1)
        m = fminf(m, __shfl_xor(m, mask));
      if (cidx == 0) umin_sh[t * 16 + (q << 2) + j][w] = m;
    }
  __syncthreads();
  // merge quarters + window. Rigorous: 2*err_u = 0.0039*xn*mw (we use
  // 2.2*0.002 = 13% margin, covers MFMA accum too); +4e-5 covers the
  // +xsq rounding bin (<=3.05e-5 for xsq in [128,256)) + 1e-5 misc.
#pragma unroll
  for (int t = 0; t < 2; ++t)
#pragma unroll
    for (int j = 0; j < 4; ++j) {
      int rl = t * 16 + (q << 2) + j;
      float mg = fminf(fminf(umin_sh[rl][0], umin_sh[rl][1]),
                       fminf(umin_sh[rl][2], umin_sh[rl][3]));
      float xn = sqrtf(xsqs[rl]) * 1.0001f;
      lim[t][j] = mg + 2.2f * (0.002f * xn * mw) + 4e-5f;
    }

  // insertion: top-2 if within window; m3 within window (or overflow) => flag
#pragma unroll
  for (int t = 0; t < 2; ++t)
#pragma unroll
    for (int j = 0; j < 4; ++j) {
      int row = blkrow + t * 16 + (q << 2) + j;
      bool ovf = false;
      if (m1[t][j] <= lim[t][j]) {
        int pos = atomicAdd(&cnt[row], 1);
        if (pos < 16) cand[(row << 4) + pos] = i1[t][j]; else ovf = true;
      }
      if (m2[t][j] <= lim[t][j]) {
        int pos = atomicAdd(&cnt[row], 1);
        if (pos < 16) cand[(row << 4) + pos] = i2[t][j]; else ovf = true;
      }
      if (ovf || m3[t][j] <= lim[t][j]) {
        int old = atomicOr(&flags[row], 1);
        if (old == 0) { int p = atomicAdd(nflag, 1); flist[p & (NROWS - 1)] = row; }
      }
    }
}

// Exact rescore: lane c replays the bit-exact np fp32 pipeline for candidate c;
// lexicographic (v, k) min == np.argmin first-occurrence. (r16/r18-r25-proven)
__global__ __launch_bounds__(256) void rescore_kernel(
    const float* __restrict__ x, const float* __restrict__ W,
    const float* __restrict__ wsq, const float* __restrict__ xsq,
    const int* __restrict__ cnt, const int* __restrict__ cand,
    const int* __restrict__ flags,
    int* __restrict__ qout, float* __restrict__ out2) {
  const int wid = threadIdx.x >> 6, lane = threadIdx.x & 63;
  const int r = blockIdx.x * 4 + wid;
  if (flags[r]) return;   // exact path owns this row
  int c = cnt[r]; if (c > 16) c = 16;
  int best;
  if (c == 1) {
    best = cand[r << 4] & (K_ - 1);
  } else {
    const float* xr = x + ((size_t)(r >> 10) * D_) * T_ + (r & 1023);
    float v = INF_; int k = 0x7fffffff;
    if (lane < c) {
      k = cand[(r << 4) + lane] & (K_ - 1);
      const float* wr = W + (size_t)k * D_;
      float mm = 0.f;
#pragma unroll 16
      for (int d = 0; d < D_; ++d)
        mm = __fmaf_rn(xr[(size_t)d * T_], wr[d], mm);   // ascending-d sgemm chain
      v = __fadd_rn(__fmaf_rn(-2.f, mm, wsq[k]), xsq[r]);  // RN(wq-2mm) then +xsq
    }
#pragma unroll
    for (int mask = 1; mask < 16; mask <<= 1) {
      float vo = __shfl_xor(v, mask); int ko = __shfl_xor(k, mask);
      if (vo < v || (vo == v && ko < k)) { v = vo; k = ko; }
    }
    best = k & (K_ - 1);
  }
  if (lane == 0) { qout[r] = best; out2[r] = (float)best; }
}

// Exact full-scan for flagged rows (expected ~0-10). Work item = (row,
// k-chunk of 512): 8-way parallel per row; partial lex-min merged via u64
// atomicMin (deterministic: same values every replay). LDS-staged coalesced W.
__global__ __launch_bounds__(256) void exact_kernel(
    const float* __restrict__ x, const float* __restrict__ W,
    const float* __restrict__ wsq, const float* __restrict__ xsq,
    const int* __restrict__ nflag, const int* __restrict__ flist,
    unsigned long long* __restrict__ eslot) {
  __shared__ float xrow[128];
  __shared__ float wl[64][130];   // pad 130
  int n = *nflag; if (n > NROWS) n = NROWS;
  for (int item = blockIdx.x; item < n * 8; item += 256) {
    int r = flist[item >> 3] & (NROWS - 1);
    int chunk = item & 7;
    const float* xr = x + ((size_t)(r >> 10) * D_) * T_ + (r & 1023);
    __syncthreads();   // protect xrow/wl from previous item
    if (threadIdx.x < 128) xrow[threadIdx.x] = xr[(size_t)threadIdx.x * T_];
    float v = INF_; int kb = 0x7fffffff;
    for (int s = chunk * 8; s < chunk * 8 + 8; ++s) {
      __syncthreads();
      const f2* src = (const f2*)(W + (size_t)s * 64 * D_);
      for (int e = threadIdx.x; e < 4096; e += 256)
        *(f2*)&wl[e >> 6][(e & 63) * 2] = src[e];
      __syncthreads();
      if (threadIdx.x < 64) {
        int k = s * 64 + threadIdx.x;
        float mm = 0.f;
#pragma unroll 16
        for (int d = 0; d < D_; ++d)
          mm = __fmaf_rn(xrow[d], wl[threadIdx.x][d], mm);  // ascending-d chain
        float vv = __fadd_rn(__fmaf_rn(-2.f, mm, wsq[k]), xsq[r]);
        if (vv < v) { v = vv; kb = k; }   // strict < ; k ascending per lane
      }
    }
    if (threadIdx.x < 64) {
#pragma unroll
      for (int mask = 1; mask < 64; mask <<= 1) {
        float vo = __shfl_xor(v, mask); int ko = __shfl_xor(kb, mask);
        if (vo < v || (vo == v && ko < kb)) { v = vo; kb = ko; }
      }
      if (threadIdx.x == 0) {
        // v > 0 (distance ~128) => float bits are order-preserving
        unsigned long long pk =
            ((unsigned long long)__float_as_uint(v) << 32) | (unsigned)kb;
        atomicMin(&eslot[r], pk);
      }
    }
    __syncthreads();
  }
}

// Write flagged rows' winners from the u64 slots.
__global__ void finalize_kernel(const int* __restrict__ flags,
                                const unsigned long long* __restrict__ eslot,
                                int* __restrict__ qout, float* __restrict__ out2) {
  int r = blockIdx.x * 256 + threadIdx.x;
  if (flags[r]) {
    int best = (int)(unsigned)(eslot[r] & 0xFFFFFFFFull) & (K_ - 1);
    qout[r] = best; out2[r] = (float)best;
  }
}

// Fused scatter (r24/r25-green): blocks [0, NROWS/2) do out0[r,d]=W[q[r],d]
// (coalesced along d); remaining B*D blocks do out1[b,d,t]=W[q[b,t],d]
// (coalesced along t).
__global__ void scatter_kernel(const float* __restrict__ W,
                               const int* __restrict__ q,
                               float* __restrict__ out0, float* __restrict__ out1) {
  if (blockIdx.x < NROWS / 2) {
    int r = blockIdx.x * 2 + (threadIdx.x >> 7);
    int d = threadIdx.x & 127;
    int k = q[r] & (K_ - 1);
    out0[(size_t)r * D_ + d] = W[(size_t)k * D_ + d];
  } else {
    int bb = blockIdx.x - NROWS / 2;
    int b = bb >> 7, d = bb & 127;
    for (int t = threadIdx.x; t < T_; t += 256) {
      int k = q[b * T_ + t] & (K_ - 1);
      out1[((size_t)b * D_ + d) * T_ + t] = W[(size_t)k * D_ + d];
    }
  }
}

extern "C" void kernel_launch(void* const* d_in, const int* in_sizes, int n_in,
                              void* d_out, int out_size, void* d_ws, size_t ws_size,
                              hipStream_t stream) {
  const float* x = (const float*)d_in[0];
  const float* W = (const float*)d_in[1];
  float* out  = (float*)d_out;
  float* out0 = out;                           // [B,T,D]  4194304
  float* out1 = out + (size_t)NROWS * D_;      // [B,D,T]  4194304
  float* out2 = out + 2 * (size_t)NROWS * D_;  // [B,T]    32768 (as float)

  // small scratch in ws (532 KB, within the proven envelope)
  float*    wsq   = (float*)d_ws;                               // 16 KB
  float*    xsq   = (float*)((char*)d_ws + (16 << 10));         // 128 KB
  int*      q     = (int*)((char*)d_ws + (144 << 10));          // 128 KB
  int*      cnt   = (int*)((char*)d_ws + (272 << 10));          // 128 KB
  unsigned* maxw  = (unsigned*)((char*)d_ws + (400 << 10));     // 4 B (4K pad)
  int*      flags = (int*)((char*)d_ws + (404 << 10));          // 128 KB

  // big scratch in out0 (read before scatter overwrites it; stream-ordered)
  int*      cand  = (int*)out0;                                    // 2 MB
  _Float16* Wbf   = (_Float16*)((char*)(void*)out0 + (2 << 20));   // 1 MB
  int*      flist = (int*)((char*)(void*)out0 + (3 << 20));        // 128 KB (also LDB overread slack)
  int*      nflag = (int*)((char*)(void*)out0 + (3 << 20) + (128 << 10));  // 64 B
  unsigned long long* eslot =
      (unsigned long long*)((char*)(void*)out0 + (3 << 20) + (256 << 10));  // 256 KB

  // maxw must be zero BEFORE prep's atomicMax (cross-block race if done inside)
  hipMemsetAsync(maxw, 0, 64, stream);
  prep_kernel<<<K_ * D_ / 256, 256, 0, stream>>>(W, Wbf, wsq, maxw,
                                                 cnt, flags, eslot, nflag);
  filter_kernel<<<NROWS / 32, 256, 0, stream>>>(x, Wbf, wsq, maxw, xsq,
                                                cnt, cand, flags, nflag, flist);
  rescore_kernel<<<NROWS / 4, 256, 0, stream>>>(x, W, wsq, xsq, cnt, cand, flags, q, out2);
  exact_kernel<<<256, 256, 0, stream>>>(x, W, wsq, xsq, nflag, flist, eslot);
  finalize_kernel<<<NROWS / 256, 256, 0, stream>>>(flags, eslot, q, out2);
  scatter_kernel<<<NROWS / 2 + B_ * D_, 256, 0, stream>>>(W, q, out0, out1);
}